// Round 1
// baseline (835.293 us; speedup 1.0000x reference)
//
#include <hip/hip_runtime.h>
#include <hip/hip_bf16.h>
#include <cstdint>

// DeepDDT forward on MI355X.
// Stages (all on `stream`):
//  0. memset S1/S2/colsum area; convert x + all weights to bf16; colsum(x).
//  1. node 0: calc GEMM -> outs0 ; attn GEMM (fused p-reduction) ; colsum(outs0)
//  2. nodes 1,2 (share inp=[outs0,x]): one calc GEMM (N=1024) -> outs1,outs2 ;
//     one attn GEMM (N=2048, fused) ; colsums
//  3. nodes 3..6: two calc + two attn GEMMs ; colsums
//  4. nodes 7..14: four attn GEMMs only (outs[7..14] are dead in the reference)
//  5. finalize: p=S2/S1 per node, tree product -> leaf probs, @leaf_out, softmax.

#define NROWS 8192
#define HALFD 512

typedef __bf16 bf16x8 __attribute__((ext_vector_type(8)));
typedef short  short8 __attribute__((ext_vector_type(8)));
typedef float  f32x4  __attribute__((ext_vector_type(4)));

union FragU { short8 s; bf16x8 b; };

__device__ __forceinline__ void gl2lds16(const void* g, void* l) {
  // async global->LDS, 16B/lane; LDS dest = wave-uniform base + lane*16
  __builtin_amdgcn_global_load_lds((__attribute__((address_space(1))) void*)g,
                                   (__attribute__((address_space(3))) void*)l,
                                   16, 0, 0);
}

// ---------------- fp32 -> bf16 convert (4 elems/thread) ----------------
__global__ void k_f32_to_bf16(const float* __restrict__ s,
                              __hip_bfloat16* __restrict__ d, int n) {
  int i = (blockIdx.x * 256 + threadIdx.x) * 4;
  if (i >= n) return;
  float4 v = *(const float4*)(s + i);
  union { short4 s4; __hip_bfloat16 h[4]; } u;
  u.h[0] = __float2bfloat16(v.x);
  u.h[1] = __float2bfloat16(v.y);
  u.h[2] = __float2bfloat16(v.z);
  u.h[3] = __float2bfloat16(v.w);
  *(short4*)(d + i) = u.s4;
}

// ---------------- column sums over 8192 rows of a [8192,512] matrix ----------------
__global__ void k_colsum_f32(const float* __restrict__ src, float* __restrict__ dst) {
  int c  = blockIdx.x * 256 + threadIdx.x;   // grid.x = 2 -> 512 cols
  int r0 = blockIdx.y * 256;                 // grid.y = 32
  float s = 0.f;
  for (int r = 0; r < 256; ++r) s += src[(size_t)(r0 + r) * HALFD + c];
  atomicAdd(&dst[c], s);
}
__global__ void k_colsum_bf16(const __hip_bfloat16* __restrict__ src, float* __restrict__ dst) {
  int c  = blockIdx.x * 256 + threadIdx.x;
  int r0 = blockIdx.y * 256;
  float s = 0.f;
  for (int r = 0; r < 256; ++r) s += __bfloat162float(src[(size_t)(r0 + r) * HALFD + c]);
  atomicAdd(&dst[c], s);
}

// ---------------- bf16 MFMA GEMM, 128x128 tile, BK=64, fused epilogues ----------------
// C[m,n] = sum_k A[m,k] * B[n,k]   (A = inp split in two 512-col halves, B = weights [N,K])
// MODE 0 (CALC): out = bf16(relu(C + bias[n])), stored to outB + (n>>9)*8192*512
// MODE 1 (ATTN): per row: S1 += sum_n e^{C+ab}, S2 += sum_n sigmoid(pw*(inp-cm))*e^{C+ab}
template <int MODE>
__global__ __launch_bounds__(256, 2)
void k_gemm(const __hip_bfloat16* __restrict__ Ah0,
            const __hip_bfloat16* __restrict__ Ah1,
            const __hip_bfloat16* __restrict__ Bw,
            int K,
            const float* __restrict__ bias,
            __hip_bfloat16* __restrict__ outB,
            const float* __restrict__ pw,
            const float* __restrict__ cm0,   // colsum of parent outs half
            const float* __restrict__ cm1,   // colsum of x
            float* __restrict__ S1,
            float* __restrict__ S2) {
  __shared__ alignas(16) short As[128 * 64];
  __shared__ alignas(16) short Bs[128 * 64];

  const int tid  = threadIdx.x;
  const int lane = tid & 63;
  const int wv   = tid >> 6;
  const int wm   = wv >> 1, wn = wv & 1;
  const int lr   = lane & 15, lg = lane >> 4;
  const int row0 = blockIdx.y * 128;
  const int col0 = blockIdx.x * 128;

  f32x4 acc[4][4];
#pragma unroll
  for (int i = 0; i < 4; ++i)
#pragma unroll
    for (int j = 0; j < 4; ++j)
#pragma unroll
      for (int e = 0; e < 4; ++e) acc[i][j][e] = 0.f;

  const int sr = tid >> 3;        // staging row (0..31 per round)
  const int sc = (tid & 7) * 8;   // staging col offset (elements)

  for (int kt = 0; kt < K; kt += 64) {
    const __hip_bfloat16* Asrc = (kt < HALFD) ? Ah0 : Ah1;
    const int kl = kt & (HALFD - 1);
    __syncthreads();
#pragma unroll
    for (int rnd = 0; rnd < 4; ++rnd) {
      const int r = rnd * 32 + sr;
      gl2lds16(Asrc + (size_t)(row0 + r) * HALFD + kl + sc,
               (char*)As + rnd * 4096 + wv * 1024);
      gl2lds16(Bw + (size_t)(col0 + r) * K + kt + sc,
               (char*)Bs + rnd * 4096 + wv * 1024);
    }
    __syncthreads();
#pragma unroll
    for (int kk = 0; kk < 64; kk += 32) {
      FragU a[4], b[4];
#pragma unroll
      for (int mi = 0; mi < 4; ++mi)
        a[mi].s = *(const short8*)(As + (wm * 64 + mi * 16 + lr) * 64 + kk + lg * 8);
#pragma unroll
      for (int ni = 0; ni < 4; ++ni)
        b[ni].s = *(const short8*)(Bs + (wn * 64 + ni * 16 + lr) * 64 + kk + lg * 8);
#pragma unroll
      for (int mi = 0; mi < 4; ++mi)
#pragma unroll
        for (int ni = 0; ni < 4; ++ni)
          acc[mi][ni] = __builtin_amdgcn_mfma_f32_16x16x32_bf16(a[mi].b, b[ni].b,
                                                               acc[mi][ni], 0, 0, 0);
    }
  }

  if constexpr (MODE == 0) {
    // CALC epilogue: relu + bias, store bf16 into outs buffer(s)
#pragma unroll
    for (int ni = 0; ni < 4; ++ni) {
      const int col  = col0 + wn * 64 + ni * 16 + lr;
      const float bv = bias[col];
      __hip_bfloat16* op = outB + (size_t)(col >> 9) * ((size_t)NROWS * HALFD) + (col & 511);
#pragma unroll
      for (int mi = 0; mi < 4; ++mi) {
#pragma unroll
        for (int rg = 0; rg < 4; ++rg) {
          const int row = row0 + wm * 64 + mi * 16 + lg * 4 + rg;
          float v = acc[mi][ni][rg] + bv;
          v = v > 0.f ? v : 0.f;
          op[(size_t)row * HALFD] = __float2bfloat16(v);
        }
      }
    }
  } else {
    // ATTN epilogue: p-numerator/denominator partial sums, atomically accumulated
    const int node = col0 >> 10;                  // which of the (up to) 2 nodes
    float* s1p = S1 + (size_t)node * NROWS;
    float* s2p = S2 + (size_t)node * NROWS;
    float bv[4], pwv[4], cmv[4];
    const __hip_bfloat16* Ain[4];
#pragma unroll
    for (int ni = 0; ni < 4; ++ni) {
      const int col = col0 + wn * 64 + ni * 16 + lr;
      bv[ni]  = bias[col];
      pwv[ni] = pw[col];
      const int ii   = col & 1023;     // index into inp
      const int half = ii >> 9;
      const int cc   = ii & 511;
      cmv[ni] = (half ? cm1[cc] : cm0[cc]) * (1.f / 8192.f);
      Ain[ni] = (half ? Ah1 : Ah0) + cc;
    }
#pragma unroll
    for (int mi = 0; mi < 4; ++mi) {
#pragma unroll
      for (int rg = 0; rg < 4; ++rg) {
        const int row = row0 + wm * 64 + mi * 16 + lg * 4 + rg;
        float s1 = 0.f, s2 = 0.f;
#pragma unroll
        for (int ni = 0; ni < 4; ++ni) {
          const float l = acc[mi][ni][rg] + bv[ni];
          const float e = __expf(l);
          const float inpv = __bfloat162float(Ain[ni][(size_t)row * HALFD]);
          const float z = pwv[ni] * (inpv - cmv[ni]);   // pw*inp + comp
          const float dist = 1.f / (1.f + __expf(-z));
          s1 += e;
          s2 += dist * e;
        }
#pragma unroll
        for (int off = 1; off < 16; off <<= 1) {
          s1 += __shfl_xor(s1, off);
          s2 += __shfl_xor(s2, off);
        }
        if (lr == 0) {
          atomicAdd(&s1p[row], s1);
          atomicAdd(&s2p[row], s2);
        }
      }
    }
  }
}

// ---------------- finalize: tree product, leaf matmul, softmax ----------------
__global__ void k_finalize(const float* __restrict__ S1, const float* __restrict__ S2,
                           const float* __restrict__ leaf_out, float* __restrict__ out) {
  const int gw   = (blockIdx.x * 256 + threadIdx.x) >> 6;  // row (one wave per row)
  const int lane = threadIdx.x & 63;
  const int r = gw;
  float pb[31];
  pb[0] = 1.f;
#pragma unroll
  for (int n = 0; n < 15; ++n) {
    const float p = S2[(size_t)n * NROWS + r] / S1[(size_t)n * NROWS + r];
    pb[2 * n + 1] = pb[n] * (1.f - p);
    pb[2 * n + 2] = pb[n] * p;
  }
  float a = 0.f;
#pragma unroll
  for (int i = 0; i < 16; ++i) a += pb[15 + i] * leaf_out[i * 64 + lane];
  float m = a;
#pragma unroll
  for (int off = 1; off < 64; off <<= 1) m = fmaxf(m, __shfl_xor(m, off));
  const float e = __expf(a - m);
  float s = e;
#pragma unroll
  for (int off = 1; off < 64; off <<= 1) s += __shfl_xor(s, off);
  out[(size_t)r * 64 + lane] = e / s;
}

// ---------------- workspace layout (bytes) ----------------
static constexpr size_t O_S1   = 0;                               // 15*8192 f32
static constexpr size_t O_S2   = O_S1 + (size_t)15 * NROWS * 4;   // 491520
static constexpr size_t O_XSUM = O_S2 + (size_t)15 * NROWS * 4;   // 983040
static constexpr size_t O_CS   = O_XSUM + 512 * 4;                // 985088 (7 x 512 f32)
static constexpr size_t O_ZEND = O_CS + 7 * 512 * 4;              // 999424 (memset range)
static constexpr size_t O_XB   = O_ZEND;                          // bf16 x [8192,512]
static constexpr size_t O_OUTS = O_XB + (size_t)NROWS * HALFD * 2;
static constexpr size_t O_CW0  = O_OUTS + 7 * (size_t)NROWS * HALFD * 2;
static constexpr size_t O_AW0  = O_CW0 + (size_t)512 * 512 * 2;
static constexpr size_t O_CW   = O_AW0 + (size_t)512 * 512 * 2;
static constexpr size_t O_AW   = O_CW + (size_t)14 * 512 * 1024 * 2;

extern "C" void kernel_launch(void* const* d_in, const int* in_sizes, int n_in,
                              void* d_out, int out_size, void* d_ws, size_t ws_size,
                              hipStream_t stream) {
  const float* x        = (const float*)d_in[0];
  const float* calc_b0  = (const float*)d_in[2];
  const float* prob_w0  = (const float*)d_in[3];
  const float* attn_b0  = (const float*)d_in[5];
  const float* calc_b   = (const float*)d_in[7];
  const float* prob_w   = (const float*)d_in[8];
  const float* attn_b   = (const float*)d_in[10];
  const float* leaf_out = (const float*)d_in[11];
  float* out = (float*)d_out;
  char* ws = (char*)d_ws;

  float* S1   = (float*)(ws + O_S1);
  float* S2   = (float*)(ws + O_S2);
  float* xsum = (float*)(ws + O_XSUM);
  float* cs   = (float*)(ws + O_CS);  // cs + n*512 = colsum of outs[n]
  __hip_bfloat16* xb   = (__hip_bfloat16*)(ws + O_XB);
  __hip_bfloat16* outs = (__hip_bfloat16*)(ws + O_OUTS);
  __hip_bfloat16* cW0b = (__hip_bfloat16*)(ws + O_CW0);
  __hip_bfloat16* aW0b = (__hip_bfloat16*)(ws + O_AW0);
  __hip_bfloat16* cWb  = (__hip_bfloat16*)(ws + O_CW);
  __hip_bfloat16* aWb  = (__hip_bfloat16*)(ws + O_AW);
  const size_t OSZ = (size_t)NROWS * HALFD;  // elements per outs buffer

  hipMemsetAsync(d_ws, 0, O_ZEND, stream);

  auto cvt = [&](const float* s, __hip_bfloat16* d, int n) {
    k_f32_to_bf16<<<dim3((n / 4 + 255) / 256), 256, 0, stream>>>(s, d, n);
  };
  cvt(x, xb, NROWS * HALFD);
  cvt((const float*)d_in[1], cW0b, 512 * 512);
  cvt((const float*)d_in[4], aW0b, 512 * 512);
  cvt((const float*)d_in[6], cWb, 14 * 512 * 1024);
  cvt((const float*)d_in[9], aWb, 14 * 1024 * 1024);
  k_colsum_f32<<<dim3(2, 32), 256, 0, stream>>>(x, xsum);

  auto calcG = [&](const __hip_bfloat16* A0, const __hip_bfloat16* A1,
                   const __hip_bfloat16* Bw, int K, int N,
                   const float* bp, __hip_bfloat16* ob) {
    k_gemm<0><<<dim3(N / 128, 64), 256, 0, stream>>>(A0, A1, Bw, K, bp, ob,
                                                     nullptr, nullptr, nullptr,
                                                     nullptr, nullptr);
  };
  auto attnG = [&](const __hip_bfloat16* A0, const __hip_bfloat16* A1,
                   const __hip_bfloat16* Bw, int K, int N,
                   const float* bp, const float* pwp,
                   const float* c0, int nodeBase) {
    k_gemm<1><<<dim3(N / 128, 64), 256, 0, stream>>>(A0, A1, Bw, K, bp, nullptr,
                                                     pwp, c0, xsum,
                                                     S1 + (size_t)nodeBase * NROWS,
                                                     S2 + (size_t)nodeBase * NROWS);
  };
  auto colsum = [&](const __hip_bfloat16* o, float* dst) {
    k_colsum_bf16<<<dim3(2, 32), 256, 0, stream>>>(o, dst);
  };

  // ---- stage 0: root (node 0), inp = x (K=512) ----
  calcG(xb, nullptr, cW0b, 512, 512, calc_b0, outs + 0 * OSZ);
  attnG(xb, nullptr, aW0b, 512, 512, attn_b0, prob_w0, xsum, 0);
  colsum(outs + 0 * OSZ, cs + 0 * 512);

  // ---- stage 1: nodes 1,2 (idx 0,1), inp = [outs0, x] ----
  calcG(outs + 0 * OSZ, xb, cWb, 1024, 1024, calc_b, outs + 1 * OSZ);
  attnG(outs + 0 * OSZ, xb, aWb, 1024, 2048, attn_b, prob_w, cs + 0 * 512, 1);
  colsum(outs + 1 * OSZ, cs + 1 * 512);
  colsum(outs + 2 * OSZ, cs + 2 * 512);

  // ---- stage 2: nodes 3,4 (idx 2,3) from outs1 ; nodes 5,6 (idx 4,5) from outs2 ----
  calcG(outs + 1 * OSZ, xb, cWb + (size_t)2 * 512 * 1024, 1024, 1024,
        calc_b + 2 * 512, outs + 3 * OSZ);
  calcG(outs + 2 * OSZ, xb, cWb + (size_t)4 * 512 * 1024, 1024, 1024,
        calc_b + 4 * 512, outs + 5 * OSZ);
  attnG(outs + 1 * OSZ, xb, aWb + (size_t)2 * 1024 * 1024, 1024, 2048,
        attn_b + 2 * 1024, prob_w + 2 * 1024, cs + 1 * 512, 3);
  attnG(outs + 2 * OSZ, xb, aWb + (size_t)4 * 1024 * 1024, 1024, 2048,
        attn_b + 4 * 1024, prob_w + 4 * 1024, cs + 2 * 512, 5);
  colsum(outs + 3 * OSZ, cs + 3 * 512);
  colsum(outs + 4 * OSZ, cs + 4 * 512);
  colsum(outs + 5 * OSZ, cs + 5 * 512);
  colsum(outs + 6 * OSZ, cs + 6 * 512);

  // ---- stage 3: nodes 7..14 (idx 6..13), attn only (outs[7..14] are dead) ----
  attnG(outs + 3 * OSZ, xb, aWb + (size_t)6 * 1024 * 1024, 1024, 2048,
        attn_b + 6 * 1024, prob_w + 6 * 1024, cs + 3 * 512, 7);
  attnG(outs + 4 * OSZ, xb, aWb + (size_t)8 * 1024 * 1024, 1024, 2048,
        attn_b + 8 * 1024, prob_w + 8 * 1024, cs + 4 * 512, 9);
  attnG(outs + 5 * OSZ, xb, aWb + (size_t)10 * 1024 * 1024, 1024, 2048,
        attn_b + 10 * 1024, prob_w + 10 * 1024, cs + 5 * 512, 11);
  attnG(outs + 6 * OSZ, xb, aWb + (size_t)12 * 1024 * 1024, 1024, 2048,
        attn_b + 12 * 1024, prob_w + 12 * 1024, cs + 6 * 512, 13);

  // ---- finalize ----
  k_finalize<<<NROWS * 64 / 256, 256, 0, stream>>>(S1, S2, leaf_out, out);
}

// Round 2
// 614.960 us; speedup vs baseline: 1.3583x; 1.3583x over previous
//
#include <hip/hip_runtime.h>
#include <hip/hip_bf16.h>
#include <cstdint>

// DeepDDT forward on MI355X.
//  - outs[7..14] are dead in the reference -> only attn GEMMs for nodes 7..14.
//  - comp = -pw * colmean(inp): one colsum per distinct inp, pw factored out.
//  - softmax+dist+sum fused into attn GEMM epilogue (S1=sum e, S2=sum dist*e).
//  - LDS chunk-XOR swizzle to kill bank conflicts (global_load_lds forces
//    contiguous lane order, so we permute WHICH global chunk each lane stages).
//  - independent GEMMs merged into one dispatch via grid.z for block drift.

#define NROWS 8192
#define HALFD 512

typedef __bf16 bf16x8 __attribute__((ext_vector_type(8)));
typedef short  short8 __attribute__((ext_vector_type(8)));
typedef float  f32x4  __attribute__((ext_vector_type(4)));

union FragU { short8 s; bf16x8 b; };

struct GArgs {
  const __hip_bfloat16* A0[4];
  const __hip_bfloat16* Bw[4];
  const float* bias[4];
  const float* pw[4];
  const float* cm0[4];
  __hip_bfloat16* outB[4];
  float* S1[4];
  float* S2[4];
};

__device__ __forceinline__ void gl2lds16(const void* g, void* l) {
  __builtin_amdgcn_global_load_lds((__attribute__((address_space(1))) void*)g,
                                   (__attribute__((address_space(3))) void*)l,
                                   16, 0, 0);
}

// ---------------- fp32 -> bf16 convert (4 elems/thread) ----------------
__global__ void k_f32_to_bf16(const float* __restrict__ s,
                              __hip_bfloat16* __restrict__ d, int n) {
  int i = (blockIdx.x * 256 + threadIdx.x) * 4;
  if (i >= n) return;
  float4 v = *(const float4*)(s + i);
  union { short4 s4; __hip_bfloat16 h[4]; } u;
  u.h[0] = __float2bfloat16(v.x);
  u.h[1] = __float2bfloat16(v.y);
  u.h[2] = __float2bfloat16(v.z);
  u.h[3] = __float2bfloat16(v.w);
  *(short4*)(d + i) = u.s4;
}

// ---------------- column sums over 8192 rows of [8192,512] matrices ----------------
__global__ void k_colsum_f32(const float* __restrict__ src, float* __restrict__ dst) {
  int c  = blockIdx.x * 256 + threadIdx.x;   // grid.x = 2 -> 512 cols
  int r0 = blockIdx.y * 256;                 // grid.y = 32
  float s = 0.f;
  for (int r = 0; r < 256; ++r) s += src[(size_t)(r0 + r) * HALFD + c];
  atomicAdd(&dst[c], s);
}
// z-merged: matrix z lives at src0 + z*NROWS*HALFD, dst0 + z*512
__global__ void k_colsum_bf16(const __hip_bfloat16* __restrict__ src0,
                              float* __restrict__ dst0) {
  const __hip_bfloat16* src = src0 + (size_t)blockIdx.z * NROWS * HALFD;
  float* dst = dst0 + (size_t)blockIdx.z * 512;
  int c  = blockIdx.x * 256 + threadIdx.x;
  int r0 = blockIdx.y * 256;
  float s = 0.f;
  for (int r = 0; r < 256; ++r) s += __bfloat162float(src[(size_t)(r0 + r) * HALFD + c]);
  atomicAdd(&dst[c], s);
}

// ---------------- bf16 MFMA GEMM, 128x128 tile, BK=64, swizzled LDS ----------------
// C[m,n] = sum_k A[m,k]*B[n,k]; A = [Ah0 | A1] two 512-col halves; B = weights [N,K].
// MODE 0 (CALC): out = bf16(relu(C+bias[n])) -> outB[z] + (n>>9)*8192*512
// MODE 1 (ATTN): per row: S1 += sum_n e^{C+ab}; S2 += sum_n sigmoid(pw*(inp-cm))*e^{C+ab}
template <int MODE>
__global__ __launch_bounds__(256, 2)
void k_gemm(GArgs ga, const __hip_bfloat16* __restrict__ A1,
            const float* __restrict__ cm1, int K) {
  __shared__ alignas(16) short As[128 * 64];
  __shared__ alignas(16) short Bs[128 * 64];

  const int z = blockIdx.z;
  const __hip_bfloat16* __restrict__ Ah0 = ga.A0[z];
  const __hip_bfloat16* __restrict__ Bw  = ga.Bw[z];
  const float* __restrict__ bias = ga.bias[z];

  const int tid  = threadIdx.x;
  const int lane = tid & 63;
  const int wv   = tid >> 6;
  const int wm   = wv >> 1, wn = wv & 1;
  const int lr   = lane & 15, lg = lane >> 4;
  const int row0 = blockIdx.y * 128;
  const int col0 = blockIdx.x * 128;

  f32x4 acc[4][4];
#pragma unroll
  for (int i = 0; i < 4; ++i)
#pragma unroll
    for (int j = 0; j < 4; ++j)
#pragma unroll
      for (int e = 0; e < 4; ++e) acc[i][j][e] = 0.f;

  const int sr = tid >> 3;                          // staging row (0..31 per round)
  const int sc = (((tid & 7) ^ (sr & 7)) << 3);     // XOR-swizzled source chunk
  const int sw = lr & 7;                            // reader's row-swizzle key

  for (int kt = 0; kt < K; kt += 64) {
    const __hip_bfloat16* Asrc = (kt < HALFD) ? Ah0 : A1;
    const int kl = kt & (HALFD - 1);
    __syncthreads();
#pragma unroll
    for (int rnd = 0; rnd < 4; ++rnd) {
      const int r = rnd * 32 + sr;
      gl2lds16(Asrc + (size_t)(row0 + r) * HALFD + kl + sc,
               (char*)As + rnd * 4096 + wv * 1024);
      gl2lds16(Bw + (size_t)(col0 + r) * K + kt + sc,
               (char*)Bs + rnd * 4096 + wv * 1024);
    }
    __syncthreads();
#pragma unroll
    for (int kk = 0; kk < 64; kk += 32) {
      FragU a[4], b[4];
#pragma unroll
      for (int mi = 0; mi < 4; ++mi)
        a[mi].s = *(const short8*)(As + (wm * 64 + mi * 16 + lr) * 64 +
                                   ((((kk >> 3) + lg) ^ sw) << 3));
#pragma unroll
      for (int ni = 0; ni < 4; ++ni)
        b[ni].s = *(const short8*)(Bs + (wn * 64 + ni * 16 + lr) * 64 +
                                   ((((kk >> 3) + lg) ^ sw) << 3));
#pragma unroll
      for (int mi = 0; mi < 4; ++mi)
#pragma unroll
        for (int ni = 0; ni < 4; ++ni)
          acc[mi][ni] = __builtin_amdgcn_mfma_f32_16x16x32_bf16(a[mi].b, b[ni].b,
                                                               acc[mi][ni], 0, 0, 0);
    }
  }

  if constexpr (MODE == 0) {
    __hip_bfloat16* outB = ga.outB[z];
#pragma unroll
    for (int ni = 0; ni < 4; ++ni) {
      const int col  = col0 + wn * 64 + ni * 16 + lr;
      const float bv = bias[col];
      __hip_bfloat16* op = outB + (size_t)(col >> 9) * ((size_t)NROWS * HALFD) + (col & 511);
#pragma unroll
      for (int mi = 0; mi < 4; ++mi) {
#pragma unroll
        for (int rg = 0; rg < 4; ++rg) {
          const int row = row0 + wm * 64 + mi * 16 + lg * 4 + rg;
          float v = acc[mi][ni][rg] + bv;
          v = v > 0.f ? v : 0.f;
          op[(size_t)row * HALFD] = __float2bfloat16(v);
        }
      }
    }
  } else {
    const float* __restrict__ pw  = ga.pw[z];
    const float* __restrict__ cm0 = ga.cm0[z];
    const int node = col0 >> 10;                  // which of the (up to) 2 nodes in z
    float* s1p = ga.S1[z] + (size_t)node * NROWS;
    float* s2p = ga.S2[z] + (size_t)node * NROWS;
    float bv[4], pwv[4], cmv[4];
    const __hip_bfloat16* Ain[4];
#pragma unroll
    for (int ni = 0; ni < 4; ++ni) {
      const int col = col0 + wn * 64 + ni * 16 + lr;
      bv[ni]  = bias[col];
      pwv[ni] = pw[col];
      const int ii   = col & 1023;     // index into inp
      const int half = ii >> 9;
      const int cc   = ii & 511;
      cmv[ni] = (half ? cm1[cc] : cm0[cc]) * (1.f / 8192.f);
      Ain[ni] = (half ? A1 : Ah0) + cc;
    }
#pragma unroll
    for (int mi = 0; mi < 4; ++mi) {
#pragma unroll
      for (int rg = 0; rg < 4; ++rg) {
        const int row = row0 + wm * 64 + mi * 16 + lg * 4 + rg;
        float s1 = 0.f, s2 = 0.f;
#pragma unroll
        for (int ni = 0; ni < 4; ++ni) {
          const float l = acc[mi][ni][rg] + bv[ni];
          const float e = __expf(l);
          const float inpv = __bfloat162float(Ain[ni][(size_t)row * HALFD]);
          const float zz = pwv[ni] * (inpv - cmv[ni]);   // pw*inp + comp
          const float dist = 1.f / (1.f + __expf(-zz));
          s1 += e;
          s2 += dist * e;
        }
#pragma unroll
        for (int off = 1; off < 16; off <<= 1) {
          s1 += __shfl_xor(s1, off);
          s2 += __shfl_xor(s2, off);
        }
        if (lr == 0) {
          atomicAdd(&s1p[row], s1);
          atomicAdd(&s2p[row], s2);
        }
      }
    }
  }
}

// ---------------- finalize: tree product, leaf matmul, softmax ----------------
__global__ void k_finalize(const float* __restrict__ S1, const float* __restrict__ S2,
                           const float* __restrict__ leaf_out, float* __restrict__ out) {
  const int r    = (blockIdx.x * 256 + threadIdx.x) >> 6;  // one wave per row
  const int lane = threadIdx.x & 63;
  float pb[31];
  pb[0] = 1.f;
#pragma unroll
  for (int n = 0; n < 15; ++n) {
    const float p = S2[(size_t)n * NROWS + r] / S1[(size_t)n * NROWS + r];
    pb[2 * n + 1] = pb[n] * (1.f - p);
    pb[2 * n + 2] = pb[n] * p;
  }
  float a = 0.f;
#pragma unroll
  for (int i = 0; i < 16; ++i) a += pb[15 + i] * leaf_out[i * 64 + lane];
  float m = a;
#pragma unroll
  for (int off = 1; off < 64; off <<= 1) m = fmaxf(m, __shfl_xor(m, off));
  const float e = __expf(a - m);
  float s = e;
#pragma unroll
  for (int off = 1; off < 64; off <<= 1) s += __shfl_xor(s, off);
  out[(size_t)r * 64 + lane] = e / s;
}

// ---------------- workspace layout (bytes) ----------------
static constexpr size_t O_S1   = 0;                               // 15*8192 f32
static constexpr size_t O_S2   = O_S1 + (size_t)15 * NROWS * 4;
static constexpr size_t O_XSUM = O_S2 + (size_t)15 * NROWS * 4;
static constexpr size_t O_CS   = O_XSUM + 512 * 4;                // 7 x 512 f32
static constexpr size_t O_ZEND = O_CS + 7 * 512 * 4;              // memset range
static constexpr size_t O_XB   = O_ZEND;                          // bf16 x [8192,512]
static constexpr size_t O_OUTS = O_XB + (size_t)NROWS * HALFD * 2;
static constexpr size_t O_CW0  = O_OUTS + 7 * (size_t)NROWS * HALFD * 2;
static constexpr size_t O_AW0  = O_CW0 + (size_t)512 * 512 * 2;
static constexpr size_t O_CW   = O_AW0 + (size_t)512 * 512 * 2;
static constexpr size_t O_AW   = O_CW + (size_t)14 * 512 * 1024 * 2;

extern "C" void kernel_launch(void* const* d_in, const int* in_sizes, int n_in,
                              void* d_out, int out_size, void* d_ws, size_t ws_size,
                              hipStream_t stream) {
  const float* x        = (const float*)d_in[0];
  const float* calc_b0  = (const float*)d_in[2];
  const float* prob_w0  = (const float*)d_in[3];
  const float* attn_b0  = (const float*)d_in[5];
  const float* calc_b   = (const float*)d_in[7];
  const float* prob_w   = (const float*)d_in[8];
  const float* attn_b   = (const float*)d_in[10];
  const float* leaf_out = (const float*)d_in[11];
  float* out = (float*)d_out;
  char* ws = (char*)d_ws;

  float* S1   = (float*)(ws + O_S1);
  float* S2   = (float*)(ws + O_S2);
  float* xsum = (float*)(ws + O_XSUM);
  float* cs   = (float*)(ws + O_CS);  // cs + n*512 = colsum of outs[n]
  __hip_bfloat16* xb   = (__hip_bfloat16*)(ws + O_XB);
  __hip_bfloat16* outs = (__hip_bfloat16*)(ws + O_OUTS);
  __hip_bfloat16* cW0b = (__hip_bfloat16*)(ws + O_CW0);
  __hip_bfloat16* aW0b = (__hip_bfloat16*)(ws + O_AW0);
  __hip_bfloat16* cWb  = (__hip_bfloat16*)(ws + O_CW);
  __hip_bfloat16* aWb  = (__hip_bfloat16*)(ws + O_AW);
  const size_t OSZ = (size_t)NROWS * HALFD;  // elements per outs buffer

  hipMemsetAsync(d_ws, 0, O_ZEND, stream);

  auto cvt = [&](const float* s, __hip_bfloat16* d, int n) {
    k_f32_to_bf16<<<dim3((n / 4 + 255) / 256), 256, 0, stream>>>(s, d, n);
  };
  cvt(x, xb, NROWS * HALFD);
  cvt((const float*)d_in[1], cW0b, 512 * 512);
  cvt((const float*)d_in[4], aW0b, 512 * 512);
  cvt((const float*)d_in[6], cWb, 14 * 512 * 1024);
  cvt((const float*)d_in[9], aWb, 14 * 1024 * 1024);
  k_colsum_f32<<<dim3(2, 32), 256, 0, stream>>>(x, xsum);

  // z-merged calc: per z { A0, Bw, bias, outB }, N=1024 each (except root 512)
  auto calcG = [&](int nz, int N, const __hip_bfloat16* const* A0,
                   const __hip_bfloat16* const* Bw, const float* const* bp,
                   __hip_bfloat16* const* ob) {
    GArgs ga{};
    for (int i = 0; i < nz; ++i) {
      ga.A0[i] = A0[i]; ga.Bw[i] = Bw[i]; ga.bias[i] = bp[i]; ga.outB[i] = ob[i];
    }
    k_gemm<0><<<dim3(N / 128, 64, nz), 256, 0, stream>>>(ga, xb, xsum, N == 512 ? 512 : 1024);
  };
  // z-merged attn: per z { A0, Bw, bias, pw, cm0, S1/S2 base }, N=2048 (root 512)
  auto attnG = [&](int nz, int N, const __hip_bfloat16* const* A0,
                   const __hip_bfloat16* const* Bw, const float* const* bp,
                   const float* const* pwp, const float* const* c0,
                   const int* nodeBase) {
    GArgs ga{};
    for (int i = 0; i < nz; ++i) {
      ga.A0[i] = A0[i]; ga.Bw[i] = Bw[i]; ga.bias[i] = bp[i];
      ga.pw[i] = pwp[i]; ga.cm0[i] = c0[i];
      ga.S1[i] = S1 + (size_t)nodeBase[i] * NROWS;
      ga.S2[i] = S2 + (size_t)nodeBase[i] * NROWS;
    }
    k_gemm<1><<<dim3(N / 128, 64, nz), 256, 0, stream>>>(ga, xb, xsum, N == 512 ? 512 : 1024);
  };
  auto colsum = [&](int first, int cnt) {
    k_colsum_bf16<<<dim3(2, 32, cnt), 256, 0, stream>>>(outs + (size_t)first * OSZ,
                                                        cs + (size_t)first * 512);
  };

  // ---- stage 0: root (node 0), inp = x (K=512) ----
  { const __hip_bfloat16* A0[1] = {xb};  const __hip_bfloat16* Bw[1] = {cW0b};
    const float* bp[1] = {calc_b0};      __hip_bfloat16* ob[1] = {outs};
    calcG(1, 512, A0, Bw, bp, ob); }
  { const __hip_bfloat16* A0[1] = {xb};  const __hip_bfloat16* Bw[1] = {aW0b};
    const float* bp[1] = {attn_b0};      const float* pwp[1] = {prob_w0};
    const float* c0[1] = {xsum};         int nb[1] = {0};
    attnG(1, 512, A0, Bw, bp, pwp, c0, nb); }
  colsum(0, 1);

  // ---- stage 1: nodes 1,2 (idx 0,1), inp = [outs0, x] ----
  { const __hip_bfloat16* A0[1] = {outs};  const __hip_bfloat16* Bw[1] = {cWb};
    const float* bp[1] = {calc_b};         __hip_bfloat16* ob[1] = {outs + OSZ};
    calcG(1, 1024, A0, Bw, bp, ob); }
  { const __hip_bfloat16* A0[1] = {outs};  const __hip_bfloat16* Bw[1] = {aWb};
    const float* bp[1] = {attn_b};         const float* pwp[1] = {prob_w};
    const float* c0[1] = {cs};             int nb[1] = {1};
    attnG(1, 2048, A0, Bw, bp, pwp, c0, nb); }
  colsum(1, 2);

  // ---- stage 2: calc nodes 3,4 (from outs1) & 5,6 (from outs2); attn nodes 3..6 ----
  { const __hip_bfloat16* A0[2] = {outs + OSZ, outs + 2 * OSZ};
    const __hip_bfloat16* Bw[2] = {cWb + (size_t)2 * 512 * 1024, cWb + (size_t)4 * 512 * 1024};
    const float* bp[2] = {calc_b + 2 * 512, calc_b + 4 * 512};
    __hip_bfloat16* ob[2] = {outs + 3 * OSZ, outs + 5 * OSZ};
    calcG(2, 1024, A0, Bw, bp, ob); }
  { const __hip_bfloat16* A0[2] = {outs + OSZ, outs + 2 * OSZ};
    const __hip_bfloat16* Bw[2] = {aWb + (size_t)2 * 1024 * 1024, aWb + (size_t)4 * 1024 * 1024};
    const float* bp[2] = {attn_b + 2 * 1024, attn_b + 4 * 1024};
    const float* pwp[2] = {prob_w + 2 * 1024, prob_w + 4 * 1024};
    const float* c0[2] = {cs + 512, cs + 2 * 512};
    int nb[2] = {3, 5};
    attnG(2, 2048, A0, Bw, bp, pwp, c0, nb); }
  colsum(3, 4);

  // ---- stage 3: nodes 7..14 (attn only; outs[7..14] dead) ----
  { const __hip_bfloat16* A0[4] = {outs + 3 * OSZ, outs + 4 * OSZ, outs + 5 * OSZ, outs + 6 * OSZ};
    const __hip_bfloat16* Bw[4] = {aWb + (size_t)6 * 1024 * 1024, aWb + (size_t)8 * 1024 * 1024,
                                   aWb + (size_t)10 * 1024 * 1024, aWb + (size_t)12 * 1024 * 1024};
    const float* bp[4] = {attn_b + 6 * 1024, attn_b + 8 * 1024,
                          attn_b + 10 * 1024, attn_b + 12 * 1024};
    const float* pwp[4] = {prob_w + 6 * 1024, prob_w + 8 * 1024,
                           prob_w + 10 * 1024, prob_w + 12 * 1024};
    const float* c0[4] = {cs + 3 * 512, cs + 4 * 512, cs + 5 * 512, cs + 6 * 512};
    int nb[4] = {7, 9, 11, 13};
    attnG(4, 2048, A0, Bw, bp, pwp, c0, nb); }

  // ---- finalize ----
  k_finalize<<<NROWS * 64 / 256, 256, 0, stream>>>(S1, S2, leaf_out, out);
}

// Round 4
// 535.192 us; speedup vs baseline: 1.5607x; 1.1490x over previous
//
#include <hip/hip_runtime.h>
#include <hip/hip_bf16.h>
#include <cstdint>

// DeepDDT forward on MI355X.
//  - outs[7..14] dead in reference -> only attn GEMMs for nodes 7..14.
//  - comp = -pw * colmean(inp): colsum fused into calc epilogue, pw factored out.
//  - softmax+dist+sum fused into attn GEMM epilogue (S1=sum e, S2=sum dist*e).
//  - LDS chunk-XOR swizzle (0 bank conflicts, verified round 2).
//  - per stage ONE dispatch: calc+attn merged via grid.z (runtime mode), padded
//    grid.x with early exit.
//  - XCD-partitioned block swizzle: id&7 owns an 8-row y-band (A no cross-XCD
//    dup; B-tile reused 8x consecutively; working set ~2.25MB < 4MB L2/XCD).

#define NROWS 8192
#define HALFD 512

typedef __bf16 bf16x8 __attribute__((ext_vector_type(8)));
typedef short  short8 __attribute__((ext_vector_type(8)));
typedef float  f32x4  __attribute__((ext_vector_type(4)));

union FragU { short8 s; bf16x8 b; };

struct GArgs {
  const __hip_bfloat16* A0[4];
  const __hip_bfloat16* Bw[4];
  const float* bias[4];
  const float* pw[4];     // attn
  const float* cm0[4];    // attn: colsum of A0 half
  __hip_bfloat16* outB[4];// calc
  float* csOut[4];        // calc: colsum target (cs + firstOut*512)
  float* S1[4];           // attn: node-base S1
  float* S2[4];
  int mode[4];            // 0 = calc, 1 = attn
  int gx[4];              // real x-tiles for this z
  int K[4];
};

__device__ __forceinline__ void gl2lds16(const void* g, void* l) {
  __builtin_amdgcn_global_load_lds((__attribute__((address_space(1))) void*)g,
                                   (__attribute__((address_space(3))) void*)l,
                                   16, 0, 0);
}

// ---------------- merged fp32 -> bf16 convert (5 regions, 1024 elems/block) ----------------
struct CvtArgs { const float* src[5]; __hip_bfloat16* dst[5]; int nblk[5]; };
__global__ void k_cvt(CvtArgs a) {
  int b = blockIdx.x, r = 0;
  while (b >= a.nblk[r]) { b -= a.nblk[r]; ++r; }
  const int i = (b * 256 + threadIdx.x) * 4;
  float4 v = *(const float4*)(a.src[r] + i);
  union { short4 s4; __hip_bfloat16 h[4]; } u;
  u.h[0] = __float2bfloat16(v.x);
  u.h[1] = __float2bfloat16(v.y);
  u.h[2] = __float2bfloat16(v.z);
  u.h[3] = __float2bfloat16(v.w);
  *(short4*)(a.dst[r] + i) = u.s4;
}

// ---------------- column sum of fp32 x [8192,512] ----------------
__global__ void k_colsum_f32(const float* __restrict__ src, float* __restrict__ dst) {
  int c  = blockIdx.x * 256 + threadIdx.x;   // grid (2,32)
  int r0 = blockIdx.y * 256;
  float s = 0.f;
  for (int r = 0; r < 256; ++r) s += src[(size_t)(r0 + r) * HALFD + c];
  atomicAdd(&dst[c], s);
}

// ---------------- bf16 MFMA GEMM, 128x128 tile, BK=64, swizzled LDS ----------------
__global__ __launch_bounds__(256, 2)
void k_gemm(GArgs ga, const __hip_bfloat16* __restrict__ A1,
            const float* __restrict__ cm1) {
  __shared__ alignas(16) short As[128 * 64];
  __shared__ alignas(16) short Bs[128 * 64];

  const int z = blockIdx.z;
  // XCD-partitioned swizzle: xcd = id&7 owns y in [xcd*8, xcd*8+8), x slow.
  const int id  = blockIdx.x + gridDim.x * blockIdx.y;
  const int xcd = id & 7;
  const int q   = id >> 3;
  const int bx  = q >> 3;
  const int by  = xcd * 8 + (q & 7);
  if (bx >= ga.gx[z]) return;

  const __hip_bfloat16* __restrict__ Ah0 = ga.A0[z];
  const __hip_bfloat16* __restrict__ Bw  = ga.Bw[z];
  const float* __restrict__ bias = ga.bias[z];
  const int K = ga.K[z];

  const int tid  = threadIdx.x;
  const int lane = tid & 63;
  const int wv   = tid >> 6;
  const int wm   = wv >> 1, wn = wv & 1;
  const int lr   = lane & 15, lg = lane >> 4;
  const int row0 = by * 128;
  const int col0 = bx * 128;

  f32x4 acc[4][4];
#pragma unroll
  for (int i = 0; i < 4; ++i)
#pragma unroll
    for (int j = 0; j < 4; ++j)
#pragma unroll
      for (int e = 0; e < 4; ++e) acc[i][j][e] = 0.f;

  const int sr = tid >> 3;                          // staging row (0..31/round)
  const int sc = (((tid & 7) ^ (sr & 7)) << 3);     // XOR-swizzled source chunk
  const int sw = lr & 7;                            // reader's swizzle key

  for (int kt = 0; kt < K; kt += 64) {
    const __hip_bfloat16* Asrc = (kt < HALFD) ? Ah0 : A1;
    const int kl = kt & (HALFD - 1);
    __syncthreads();
#pragma unroll
    for (int rnd = 0; rnd < 4; ++rnd) {
      const int r = rnd * 32 + sr;
      gl2lds16(Asrc + (size_t)(row0 + r) * HALFD + kl + sc,
               (char*)As + rnd * 4096 + wv * 1024);
      gl2lds16(Bw + (size_t)(col0 + r) * K + kt + sc,
               (char*)Bs + rnd * 4096 + wv * 1024);
    }
    __syncthreads();
#pragma unroll
    for (int kk = 0; kk < 64; kk += 32) {
      FragU a[4], b[4];
#pragma unroll
      for (int mi = 0; mi < 4; ++mi)
        a[mi].s = *(const short8*)(As + (wm * 64 + mi * 16 + lr) * 64 +
                                   ((((kk >> 3) + lg) ^ sw) << 3));
#pragma unroll
      for (int ni = 0; ni < 4; ++ni)
        b[ni].s = *(const short8*)(Bs + (wn * 64 + ni * 16 + lr) * 64 +
                                   ((((kk >> 3) + lg) ^ sw) << 3));
#pragma unroll
      for (int mi = 0; mi < 4; ++mi)
#pragma unroll
        for (int ni = 0; ni < 4; ++ni)
          acc[mi][ni] = __builtin_amdgcn_mfma_f32_16x16x32_bf16(a[mi].b, b[ni].b,
                                                               acc[mi][ni], 0, 0, 0);
    }
  }

  if (ga.mode[z] == 0) {
    // CALC: relu+bias -> bf16 outs, fused column-sum (shuffle over lg, 1 atomic/col/wave)
    __hip_bfloat16* outB = ga.outB[z];
    float* csOut = ga.csOut[z];
#pragma unroll
    for (int ni = 0; ni < 4; ++ni) {
      const int col  = col0 + wn * 64 + ni * 16 + lr;
      const float bv = bias[col];
      __hip_bfloat16* op = outB + (size_t)(col >> 9) * ((size_t)NROWS * HALFD) + (col & 511);
      float csum = 0.f;
#pragma unroll
      for (int mi = 0; mi < 4; ++mi) {
#pragma unroll
        for (int rg = 0; rg < 4; ++rg) {
          const int row = row0 + wm * 64 + mi * 16 + lg * 4 + rg;
          float v = acc[mi][ni][rg] + bv;
          v = v > 0.f ? v : 0.f;
          csum += v;
          op[(size_t)row * HALFD] = __float2bfloat16(v);
        }
      }
      csum += __shfl_xor(csum, 16);
      csum += __shfl_xor(csum, 32);
      if (lg == 0) atomicAdd(&csOut[col], csum);
    }
  } else {
    // ATTN: S1 += sum_n e^{C+ab}; S2 += sum_n sigmoid(pw*(inp-cm))*e^{C+ab}
    const float* __restrict__ pw  = ga.pw[z];
    const float* __restrict__ cm0 = ga.cm0[z];
    const int node = col0 >> 10;                  // which of the (up to) 2 nodes in z
    float* s1p = ga.S1[z] + (size_t)node * NROWS;
    float* s2p = ga.S2[z] + (size_t)node * NROWS;
    float bv[4], pwv[4], cmv[4];
    const __hip_bfloat16* Ain[4];
#pragma unroll
    for (int ni = 0; ni < 4; ++ni) {
      const int col = col0 + wn * 64 + ni * 16 + lr;
      bv[ni]  = bias[col];
      pwv[ni] = pw[col];
      const int ii   = col & 1023;
      const int half = ii >> 9;
      const int cc   = ii & 511;
      cmv[ni] = (half ? cm1[cc] : cm0[cc]) * (1.f / 8192.f);
      Ain[ni] = (half ? A1 : Ah0) + cc;
    }
#pragma unroll
    for (int mi = 0; mi < 4; ++mi) {
#pragma unroll
      for (int rg = 0; rg < 4; ++rg) {
        const int row = row0 + wm * 64 + mi * 16 + lg * 4 + rg;
        float s1 = 0.f, s2 = 0.f;
#pragma unroll
        for (int ni = 0; ni < 4; ++ni) {
          const float l = acc[mi][ni][rg] + bv[ni];
          const float e = __expf(l);
          const float inpv = __bfloat162float(Ain[ni][(size_t)row * HALFD]);
          const float zz = pwv[ni] * (inpv - cmv[ni]);   // pw*inp + comp
          const float dist = 1.f / (1.f + __expf(-zz));
          s1 += e;
          s2 += dist * e;
        }
#pragma unroll
        for (int off = 1; off < 16; off <<= 1) {
          s1 += __shfl_xor(s1, off);
          s2 += __shfl_xor(s2, off);
        }
        if (lr == 0) {
          atomicAdd(&s1p[row], s1);
          atomicAdd(&s2p[row], s2);
        }
      }
    }
  }
}

// ---------------- finalize: tree product, leaf matmul, softmax ----------------
__global__ void k_finalize(const float* __restrict__ S1, const float* __restrict__ S2,
                           const float* __restrict__ leaf_out, float* __restrict__ out) {
  const int r    = (blockIdx.x * 256 + threadIdx.x) >> 6;  // one wave per row
  const int lane = threadIdx.x & 63;
  float pb[31];
  pb[0] = 1.f;
#pragma unroll
  for (int n = 0; n < 15; ++n) {
    const float p = S2[(size_t)n * NROWS + r] / S1[(size_t)n * NROWS + r];
    pb[2 * n + 1] = pb[n] * (1.f - p);
    pb[2 * n + 2] = pb[n] * p;
  }
  float a = 0.f;
#pragma unroll
  for (int i = 0; i < 16; ++i) a += pb[15 + i] * leaf_out[i * 64 + lane];
  float m = a;
#pragma unroll
  for (int off = 1; off < 64; off <<= 1) m = fmaxf(m, __shfl_xor(m, off));
  const float e = __expf(a - m);
  float s = e;
#pragma unroll
  for (int off = 1; off < 64; off <<= 1) s += __shfl_xor(s, off);
  out[(size_t)r * 64 + lane] = e / s;
}

// ---------------- workspace layout (bytes) ----------------
static constexpr size_t O_S1   = 0;                               // 15*8192 f32
static constexpr size_t O_S2   = O_S1 + (size_t)15 * NROWS * 4;
static constexpr size_t O_XSUM = O_S2 + (size_t)15 * NROWS * 4;
static constexpr size_t O_CS   = O_XSUM + 512 * 4;                // 7 x 512 f32
static constexpr size_t O_ZEND = O_CS + 7 * 512 * 4;              // memset range
static constexpr size_t O_XB   = O_ZEND;                          // bf16 x [8192,512]
static constexpr size_t O_OUTS = O_XB + (size_t)NROWS * HALFD * 2;
static constexpr size_t O_CW0  = O_OUTS + 7 * (size_t)NROWS * HALFD * 2;
static constexpr size_t O_AW0  = O_CW0 + (size_t)512 * 512 * 2;
static constexpr size_t O_CW   = O_AW0 + (size_t)512 * 512 * 2;
static constexpr size_t O_AW   = O_CW + (size_t)14 * 512 * 1024 * 2;

extern "C" void kernel_launch(void* const* d_in, const int* in_sizes, int n_in,
                              void* d_out, int out_size, void* d_ws, size_t ws_size,
                              hipStream_t stream) {
  const float* x        = (const float*)d_in[0];
  const float* calc_b0  = (const float*)d_in[2];
  const float* prob_w0  = (const float*)d_in[3];
  const float* attn_b0  = (const float*)d_in[5];
  const float* calc_b   = (const float*)d_in[7];
  const float* prob_w   = (const float*)d_in[8];
  const float* attn_b   = (const float*)d_in[10];
  const float* leaf_out = (const float*)d_in[11];
  float* out = (float*)d_out;
  char* ws = (char*)d_ws;

  float* S1   = (float*)(ws + O_S1);
  float* S2   = (float*)(ws + O_S2);
  float* xsum = (float*)(ws + O_XSUM);
  float* cs   = (float*)(ws + O_CS);  // cs + n*512 = colsum of outs[n]
  __hip_bfloat16* xb   = (__hip_bfloat16*)(ws + O_XB);
  __hip_bfloat16* outs = (__hip_bfloat16*)(ws + O_OUTS);
  __hip_bfloat16* cW0b = (__hip_bfloat16*)(ws + O_CW0);
  __hip_bfloat16* aW0b = (__hip_bfloat16*)(ws + O_AW0);
  __hip_bfloat16* cWb  = (__hip_bfloat16*)(ws + O_CW);
  __hip_bfloat16* aWb  = (__hip_bfloat16*)(ws + O_AW);
  const size_t OSZ = (size_t)NROWS * HALFD;  // elements per outs buffer

  hipMemsetAsync(d_ws, 0, O_ZEND, stream);

  // merged converts (elements all divisible by 1024)
  {
    CvtArgs ca{};
    ca.src[0] = x;                     ca.dst[0] = xb;   ca.nblk[0] = NROWS * HALFD / 1024;
    ca.src[1] = (const float*)d_in[1]; ca.dst[1] = cW0b; ca.nblk[1] = 512 * 512 / 1024;
    ca.src[2] = (const float*)d_in[4]; ca.dst[2] = aW0b; ca.nblk[2] = 512 * 512 / 1024;
    ca.src[3] = (const float*)d_in[6]; ca.dst[3] = cWb;  ca.nblk[3] = 14 * 512 * 1024 / 1024;
    ca.src[4] = (const float*)d_in[9]; ca.dst[4] = aWb;  ca.nblk[4] = 14 * 1024 * 1024 / 1024;
    int tot = ca.nblk[0] + ca.nblk[1] + ca.nblk[2] + ca.nblk[3] + ca.nblk[4];
    k_cvt<<<tot, 256, 0, stream>>>(ca);
  }
  k_colsum_f32<<<dim3(2, 32), 256, 0, stream>>>(x, xsum);

  // ---- stage 0: root calc + root attn (K=512, N=512) ----
  {
    GArgs ga{};
    ga.mode[0] = 0; ga.gx[0] = 4; ga.K[0] = 512;
    ga.A0[0] = xb; ga.Bw[0] = cW0b; ga.bias[0] = calc_b0;
    ga.outB[0] = outs; ga.csOut[0] = cs;
    ga.mode[1] = 1; ga.gx[1] = 4; ga.K[1] = 512;
    ga.A0[1] = xb; ga.Bw[1] = aW0b; ga.bias[1] = attn_b0;
    ga.pw[1] = prob_w0; ga.cm0[1] = xsum;
    ga.S1[1] = S1; ga.S2[1] = S2;
    k_gemm<<<dim3(4, 64, 2), 256, 0, stream>>>(ga, xb, xsum);
  }
  // ---- stage 1: calc nodes 1,2 + attn nodes 1,2 (A=[outs0|x]) ----
  {
    GArgs ga{};
    ga.mode[0] = 0; ga.gx[0] = 8; ga.K[0] = 1024;
    ga.A0[0] = outs; ga.Bw[0] = cWb; ga.bias[0] = calc_b;
    ga.outB[0] = outs + OSZ; ga.csOut[0] = cs + 512;
    ga.mode[1] = 1; ga.gx[1] = 16; ga.K[1] = 1024;
    ga.A0[1] = outs; ga.Bw[1] = aWb; ga.bias[1] = attn_b;
    ga.pw[1] = prob_w; ga.cm0[1] = cs;
    ga.S1[1] = S1 + (size_t)1 * NROWS; ga.S2[1] = S2 + (size_t)1 * NROWS;
    k_gemm<<<dim3(16, 64, 2), 256, 0, stream>>>(ga, xb, xsum);
  }
  // ---- stage 2: calc nodes 3,4 (outs1) & 5,6 (outs2) + attn nodes 3..6 ----
  {
    GArgs ga{};
    for (int i = 0; i < 2; ++i) {
      ga.mode[i] = 0; ga.gx[i] = 8; ga.K[i] = 1024;
      ga.A0[i] = outs + (size_t)(1 + i) * OSZ;
      ga.Bw[i] = cWb + (size_t)(2 + 2 * i) * 512 * 1024;
      ga.bias[i] = calc_b + (2 + 2 * i) * 512;
      ga.outB[i] = outs + (size_t)(3 + 2 * i) * OSZ;
      ga.csOut[i] = cs + (size_t)(3 + 2 * i) * 512;
    }
    for (int i = 0; i < 2; ++i) {
      const int zi = 2 + i;
      ga.mode[zi] = 1; ga.gx[zi] = 16; ga.K[zi] = 1024;
      ga.A0[zi] = outs + (size_t)(1 + i) * OSZ;
      ga.Bw[zi] = aWb + (size_t)(2 + 2 * i) * 1024 * 1024;
      ga.bias[zi] = attn_b + (2 + 2 * i) * 1024;
      ga.pw[zi] = prob_w + (2 + 2 * i) * 1024;
      ga.cm0[zi] = cs + (size_t)(1 + i) * 512;
      ga.S1[zi] = S1 + (size_t)(3 + 2 * i) * NROWS;
      ga.S2[zi] = S2 + (size_t)(3 + 2 * i) * NROWS;
    }
    k_gemm<<<dim3(16, 64, 4), 256, 0, stream>>>(ga, xb, xsum);
  }
  // ---- stage 3: attn nodes 7..14 (outs[7..14] dead) ----
  {
    GArgs ga{};
    for (int i = 0; i < 4; ++i) {
      ga.mode[i] = 1; ga.gx[i] = 16; ga.K[i] = 1024;
      ga.A0[i] = outs + (size_t)(3 + i) * OSZ;
      ga.Bw[i] = aWb + (size_t)(6 + 2 * i) * 1024 * 1024;
      ga.bias[i] = attn_b + (6 + 2 * i) * 1024;
      ga.pw[i] = prob_w + (6 + 2 * i) * 1024;
      ga.cm0[i] = cs + (size_t)(3 + i) * 512;
      ga.S1[i] = S1 + (size_t)(7 + 2 * i) * NROWS;
      ga.S2[i] = S2 + (size_t)(7 + 2 * i) * NROWS;
    }
    k_gemm<<<dim3(16, 64, 4), 256, 0, stream>>>(ga, xb, xsum);
  }

  // ---- finalize ----
  k_finalize<<<NROWS * 64 / 256, 256, 0, stream>>>(S1, S2, leaf_out, out);
}